// Round 9
// baseline (320.658 us; speedup 1.0000x reference)
//
#include <hip/hip_runtime.h>
#include <hip/hip_bf16.h>
#include <stdint.h>

#define NB 100
#define NT 500
#define CIN 300
#define COUT 500
#define M_TOT (NB * NT)       // 50000
#define BMT 256               // block tile rows
#define BNT 128               // block tile cols
#define MTIL 196              // ceil(50000/256), padded M = 50176
#define NTIL 4                // 512/128
#define KTIL 20               // 320/16
#define APAN_F 4096           // 16k x 256m floats per A panel
#define BPAN_F 2048           // 16k x 128m floats per B panel
#define A_PANELS (MTIL * KTIL)            // 3920
#define B_PANELS (NTIL * KTIL)            // 80
#define WS_NEED (((size_t)A_PANELS * APAN_F + (size_t)B_PANELS * BPAN_F) * 4)  // ~64.9 MB

__device__ __forceinline__ void gload_lds16(const void* g, void* l) {
    __builtin_amdgcn_global_load_lds(
        (const __attribute__((address_space(1))) unsigned int*)g,
        (__attribute__((address_space(3))) unsigned int*)l,
        16, 0, 0);
}

// ---- pre-transpose X,W into panels: A [mtile][kt][16 kk][256 m], B [ntile][kt][16 kk][128 m] ----
__global__ __launch_bounds__(256) void split_t(
    const float* __restrict__ X, const float* __restrict__ W, float* __restrict__ ws)
{
    const int bid = blockIdx.x;
    const int tid = threadIdx.x;
    if (bid < A_PANELS) {
        const int rowbase = (bid / KTIL) * BMT;
        const int kt = bid % KTIL;
        const int kk = tid >> 4;            // 0..15
        const int m0 = (tid & 15) * 16;     // 0..240
        const int k  = kt * 16 + kk;
        float v[16];
        #pragma unroll
        for (int j = 0; j < 16; ++j) {
            const int row = rowbase + m0 + j;
            v[j] = (row < M_TOT && k < CIN) ? X[(size_t)row * CIN + k] : 0.f;
        }
        float* out = ws + (size_t)bid * APAN_F + (size_t)kk * 256 + m0;
        #pragma unroll
        for (int c = 0; c < 4; ++c)
            *(float4*)(out + c * 4) = make_float4(v[c*4], v[c*4+1], v[c*4+2], v[c*4+3]);
    } else {
        const int wb = bid - A_PANELS;
        const int colbase = (wb / KTIL) * BNT;
        const int kt = wb % KTIL;
        const int kk = tid >> 4;            // 0..15
        const int m0 = (tid & 15) * 8;      // 0..120
        const int k  = kt * 16 + kk;
        float v[8];
        #pragma unroll
        for (int j = 0; j < 8; ++j) {
            const int row = colbase + m0 + j;
            v[j] = (row < COUT && k < CIN) ? W[(size_t)row * CIN + k] : 0.f;
        }
        float* out = ws + (size_t)A_PANELS * APAN_F + (size_t)wb * BPAN_F + (size_t)kk * 128 + m0;
        *(float4*)(out + 0) = make_float4(v[0], v[1], v[2], v[3]);
        *(float4*)(out + 4) = make_float4(v[4], v[5], v[6], v[7]);
    }
}

// ---- f32 GEMM, 16x8 micro-tile; per-output fma chain identical to rounds 1/3/8 ----
__global__ __launch_bounds__(256) void gemm_t(
    const float* __restrict__ ws, float* __restrict__ C)
{
    __shared__ __align__(16) float As[2][16][256];   // 16 KB x2
    __shared__ __align__(16) float Bs[2][16][128];   // 8 KB x2  -> 48 KB total

    const int mtile = blockIdx.x >> 2;      // ntile fastest: consecutive blocks share A panels
    const int ntile = blockIdx.x & 3;
    const int m0 = mtile * BMT, n0 = ntile * BNT;

    const int tid  = threadIdx.x;
    const int lane = tid & 63;
    const int wid  = tid >> 6;              // 4 waves: 2x2 grid of 128x64 wave tiles
    const int wmb  = (wid >> 1) << 7;       // 0 / 128
    const int wnb  = (wid & 1) << 6;        // 0 / 64
    const int ra   = (lane >> 3) << 2;      // row sub 0,4,...,28 (strip stride 32)
    const int ca   = (lane & 7) << 2;       // col sub 0,4,...,28 (strip stride 32)

    const float* Ap = ws + (size_t)(mtile * KTIL) * APAN_F;
    const float* Bp = ws + (size_t)A_PANELS * APAN_F + (size_t)(ntile * KTIL) * BPAN_F;

    float acc[16][8];
    #pragma unroll
    for (int i = 0; i < 16; ++i)
        #pragma unroll
        for (int j = 0; j < 8; ++j) acc[i][j] = 0.f;

    auto stage = [&](int buf, int kt) {
        const float* xs = Ap + (size_t)kt * APAN_F + tid * 4;
        const float* bs = Bp + (size_t)kt * BPAN_F + tid * 4;
        #pragma unroll
        for (int c = 0; c < 4; ++c)
            gload_lds16(xs + c * 1024, (char*)&As[buf][0][0] + (c * 256 + tid) * 16);
        #pragma unroll
        for (int c = 0; c < 2; ++c)
            gload_lds16(bs + c * 1024, (char*)&Bs[buf][0][0] + (c * 256 + tid) * 16);
    };

    stage(0, 0);
    __syncthreads();                        // tile 0 resident

    for (int kt = 0; kt < KTIL; ++kt) {
        const int cur = kt & 1;
        if (kt + 1 < KTIL) stage(cur ^ 1, kt + 1);   // async under this tile's FMAs

        #pragma unroll 4
        for (int k = 0; k < 16; ++k) {
            float4 av[4], bv[2];
            #pragma unroll
            for (int s = 0; s < 4; ++s)     // a strips: banks 0,4..28 distinct -> conflict-free
                av[s] = *(const float4*)&As[cur][k][wmb + ra + s * 32];
            #pragma unroll
            for (int j = 0; j < 2; ++j)     // b strips: conflict-free
                bv[j] = *(const float4*)&Bs[cur][k][wnb + ca + j * 32];
            float a[16] = {av[0].x, av[0].y, av[0].z, av[0].w,
                           av[1].x, av[1].y, av[1].z, av[1].w,
                           av[2].x, av[2].y, av[2].z, av[2].w,
                           av[3].x, av[3].y, av[3].z, av[3].w};
            float b[8]  = {bv[0].x, bv[0].y, bv[0].z, bv[0].w,
                           bv[1].x, bv[1].y, bv[1].z, bv[1].w};
            #pragma unroll
            for (int i = 0; i < 16; ++i)
                #pragma unroll
                for (int j = 0; j < 8; ++j)
                    acc[i][j] += a[i] * b[j];
        }
        __syncthreads();   // readers done + next tile's gload_lds drained
    }

    // epilogue: row = m0+wmb+s*32+ra+i, cols n0+wnb+ca+{0..3, 32..35}
    #pragma unroll
    for (int s = 0; s < 4; ++s) {
        #pragma unroll
        for (int i = 0; i < 4; ++i) {
            const int m = m0 + wmb + s * 32 + ra + i;
            if (m >= M_TOT) continue;
            float* cp = C + (size_t)m * COUT;
            const int col0 = n0 + wnb + ca;       // %4==0: float4 never straddles the edge
            const int col1 = col0 + 32;
            const int ai = s * 4 + i;
            if (col0 < COUT)
                *(float4*)(cp + col0) = make_float4(acc[ai][0], acc[ai][1], acc[ai][2], acc[ai][3]);
            if (col1 < COUT)
                *(float4*)(cp + col1) = make_float4(acc[ai][4], acc[ai][5], acc[ai][6], acc[ai][7]);
        }
    }
}

// ---- fallback fp32 GEMM (round-3 proven, unchanged) ----
constexpr int BM = 128, BN = 128, BK = 32;
constexpr int LDA = BM + 4;

__global__ __launch_bounds__(256) void gemm_f32(
    const float* __restrict__ X, const float* __restrict__ W, float* __restrict__ C)
{
    __shared__ float As[BK][LDA];
    __shared__ float Bs[BK][LDA];

    const int mtile = blockIdx.x >> 2;
    const int ntile = blockIdx.x & 3;
    const int m0 = mtile * BM, n0 = ntile * BN;

    const int tid  = threadIdx.x;
    const int lane = tid & 63;
    const int wid  = tid >> 6;
    const int wmb  = (wid >> 1) << 6;
    const int wnb  = (wid & 1) << 6;
    const int r4   = (lane >> 3) << 2;
    const int c4   = (lane & 7) << 2;
    const int lr = tid >> 3;
    const int lk = (tid & 7) << 2;

    float acc[8][8];
    #pragma unroll
    for (int i = 0; i < 8; ++i)
        #pragma unroll
        for (int j = 0; j < 8; ++j) acc[i][j] = 0.f;

    for (int k0 = 0; k0 < CIN; k0 += BK) {
        const int kk = k0 + lk;
        const bool kv = (kk < CIN);
        #pragma unroll
        for (int p = 0; p < 4; ++p) {
            int row = p * 32 + lr;
            int m = m0 + row;
            float4 v = make_float4(0.f, 0.f, 0.f, 0.f);
            if (kv && m < M_TOT) v = *(const float4*)(X + (size_t)m * CIN + kk);
            As[lk + 0][row] = v.x; As[lk + 1][row] = v.y;
            As[lk + 2][row] = v.z; As[lk + 3][row] = v.w;
        }
        #pragma unroll
        for (int p = 0; p < 4; ++p) {
            int row = p * 32 + lr;
            int o = n0 + row;
            float4 v = make_float4(0.f, 0.f, 0.f, 0.f);
            if (kv && o < COUT) v = *(const float4*)(W + (size_t)o * CIN + kk);
            Bs[lk + 0][row] = v.x; Bs[lk + 1][row] = v.y;
            Bs[lk + 2][row] = v.z; Bs[lk + 3][row] = v.w;
        }
        __syncthreads();
        #pragma unroll 8
        for (int k = 0; k < BK; ++k) {
            float4 a0 = *(const float4*)&As[k][wmb + r4];
            float4 a1 = *(const float4*)&As[k][wmb + 32 + r4];
            float4 b0 = *(const float4*)&Bs[k][wnb + c4];
            float4 b1 = *(const float4*)&Bs[k][wnb + 32 + c4];
            float a[8] = {a0.x, a0.y, a0.z, a0.w, a1.x, a1.y, a1.z, a1.w};
            float b[8] = {b0.x, b0.y, b0.z, b0.w, b1.x, b1.y, b1.z, b1.w};
            #pragma unroll
            for (int i = 0; i < 8; ++i)
                #pragma unroll
                for (int j = 0; j < 8; ++j)
                    acc[i][j] += a[i] * b[j];
        }
        __syncthreads();
    }

    #pragma unroll
    for (int h = 0; h < 2; ++h) {
        #pragma unroll
        for (int i = 0; i < 4; ++i) {
            const int m = m0 + wmb + h * 32 + r4 + i;
            if (m >= M_TOT) continue;
            float* cp = C + (size_t)m * COUT;
            const int col0 = n0 + wnb + c4;
            const int col1 = col0 + 32;
            const int ai = h * 4 + i;
            if (col0 < COUT)
                *(float4*)(cp + col0) = make_float4(acc[ai][0], acc[ai][1], acc[ai][2], acc[ai][3]);
            if (col1 < COUT)
                *(float4*)(cp + col1) = make_float4(acc[ai][4], acc[ai][5], acc[ai][6], acc[ai][7]);
        }
    }
}

// ---- LIF scan, in place over C (identical source to all passing rounds). threshold == 1 ----
__global__ __launch_bounds__(256) void lif_scan(
    const float* __restrict__ alpha, float* __restrict__ C)
{
    const int n = blockIdx.x * blockDim.x + threadIdx.x;
    if (n >= NB * COUT) return;
    const int b = n / COUT, o = n % COUT;
    const float a = alpha[n];
    float v = 0.f;
    float* p = C + (size_t)b * NT * COUT + o;

    constexpr int U = 10;
    for (int t0 = 0; t0 < NT; t0 += U) {
        float xl[U];
        #pragma unroll
        for (int u = 0; u < U; ++u) xl[u] = p[(size_t)(t0 + u) * COUT];
        float s[U];
        #pragma unroll
        for (int u = 0; u < U; ++u) {
            float vp = a * v + xl[u];
            vp = fmaxf(vp, -1.f);
            float sp = (vp >= 1.f) ? floorf(vp) : 0.f;
            v = vp - sp;
            s[u] = sp;
        }
        #pragma unroll
        for (int u = 0; u < U; ++u) p[(size_t)(t0 + u) * COUT] = s[u];
    }
}

extern "C" void kernel_launch(void* const* d_in, const int* in_sizes, int n_in,
                              void* d_out, int out_size, void* d_ws, size_t ws_size,
                              hipStream_t stream) {
    const float* X     = (const float*)d_in[0];   // [100,500,300]
    const float* W     = (const float*)d_in[1];   // [500,300]
    const float* alpha = (const float*)d_in[2];   // [50000]
    float* C = (float*)d_out;                     // [100,500,500]

    if (ws_size >= WS_NEED && d_ws != nullptr) {
        float* ws = (float*)d_ws;
        split_t<<<dim3(A_PANELS + B_PANELS), dim3(256), 0, stream>>>(X, W, ws);
        gemm_t<<<dim3(MTIL * NTIL), dim3(256), 0, stream>>>(ws, C);
    } else {
        const int mtiles = (M_TOT + BM - 1) / BM;
        gemm_f32<<<dim3(mtiles * 4), dim3(256), 0, stream>>>(X, W, C);
    }

    const int nneur = NB * COUT;
    lif_scan<<<dim3((nneur + 255) / 256), dim3(256), 0, stream>>>(alpha, C);
}

// Round 10
// 289.389 us; speedup vs baseline: 1.1081x; 1.1081x over previous
//
#include <hip/hip_runtime.h>
#include <hip/hip_bf16.h>
#include <stdint.h>

#define NB 100
#define NT 500
#define CIN 300
#define COUT 500
#define M_TOT (NB * NT)       // 50000
#define MTILES 391            // ceil(50000/128)
#define NTILES 4              // 512/128
#define KTILES 10             // panels of 32 k
#define KT16 19               // 19 x 16 = 304 >= 300 (k 300..303 zero no-ops)
#define NPANEL (MTILES * KTILES + NTILES * KTILES)   // 3950 panels of 4096 floats
#define WS_NEED ((size_t)NPANEL * 4096 * 4)          // 64,716,800 B

__device__ __forceinline__ void gload_lds16(const void* g, void* l) {
    __builtin_amdgcn_global_load_lds(
        (const __attribute__((address_space(1))) unsigned int*)g,
        (__attribute__((address_space(3))) unsigned int*)l,
        16, 0, 0);
}

// ---- pre-transpose X,W into panelized [panel][32 kk][128 m] f32 tiles (round-8 verbatim) ----
__global__ __launch_bounds__(256) void split_t(
    const float* __restrict__ X, const float* __restrict__ W, float* __restrict__ ws)
{
    const int bid = blockIdx.x;
    const int tid = threadIdx.x;
    const float* src; int rowbase, nrows, kt;
    if (bid < MTILES * KTILES) {
        src = X; rowbase = (bid / KTILES) * 128; nrows = M_TOT; kt = bid % KTILES;
    } else {
        const int w = bid - MTILES * KTILES;
        src = W; rowbase = (w / KTILES) * 128; nrows = COUT; kt = w % KTILES;
    }
    const int kk = tid >> 3;            // 0..31
    const int m0 = (tid & 7) * 16;      // 0..112
    const int k  = kt * 32 + kk;

    float v[16];
    #pragma unroll
    for (int j = 0; j < 16; ++j) {
        const int row = rowbase + m0 + j;
        v[j] = (row < nrows && k < CIN) ? src[(size_t)row * CIN + k] : 0.f;
    }
    float* out = ws + (size_t)bid * 4096 + (size_t)kk * 128 + m0;
    #pragma unroll
    for (int c = 0; c < 4; ++c)
        *(float4*)(out + c * 4) = make_float4(v[c*4], v[c*4+1], v[c*4+2], v[c*4+3]);
}

// ---- f32 GEMM: round-8 compute pattern, triple-buffered BK=16, counted vmcnt barriers ----
__global__ __launch_bounds__(256) void gemm_t(
    const float* __restrict__ ws, float* __restrict__ C)
{
    __shared__ __align__(16) float As[3][16][128];   // 3 x 8 KB
    __shared__ __align__(16) float Bs[3][16][128];   // total 48 KB -> 3 blocks/CU

    const int mtile = blockIdx.x >> 2;      // ntile fastest: consecutive blocks share X panels
    const int ntile = blockIdx.x & 3;
    const int m0 = mtile * 128, n0 = ntile * 128;

    const int tid  = threadIdx.x;
    const int lane = tid & 63;
    const int wid  = tid >> 6;              // 4 waves: 2x2 grid of 64x64 wave tiles
    const int wmb  = (wid >> 1) << 6;       // 0 / 64
    const int wnb  = (wid & 1) << 6;        // 0 / 64
    const int r4   = (lane >> 3) << 2;      // 0,4,...,28
    const int c4   = (lane & 7) << 2;       // 0,4,...,28

    const float* Ap = ws + (size_t)(mtile * KTILES) * 4096;
    const float* Bp = ws + (size_t)(MTILES * KTILES + ntile * KTILES) * 4096;

    float acc[8][8];
    #pragma unroll
    for (int i = 0; i < 8; ++i)
        #pragma unroll
        for (int j = 0; j < 8; ++j) acc[i][j] = 0.f;

    // stage one 16-k half-panel pair into buffer buf; 4 vmcnt entries per wave
    auto stage = [&](int buf, int kt) {
        const size_t poff = (size_t)(kt >> 1) * 4096 + (size_t)(kt & 1) * 2048 + tid * 4;
        const float* xs = Ap + poff;
        const float* bs = Bp + poff;
        #pragma unroll
        for (int c = 0; c < 2; ++c) {
            gload_lds16(xs + c * 1024, (char*)&As[buf][0][0] + (size_t)(c * 256 + tid) * 16);
            gload_lds16(bs + c * 1024, (char*)&Bs[buf][0][0] + (size_t)(c * 256 + tid) * 16);
        }
    };

    stage(0, 0);
    stage(1, 1);
    asm volatile("s_waitcnt vmcnt(4)" ::: "memory");   // tile 0 resident; tile 1 in flight
    __builtin_amdgcn_s_barrier();
    asm volatile("" ::: "memory");

    for (int kt = 0; kt < KT16; ++kt) {
        const int cur = kt % 3;
        if (kt + 2 < KT16) stage((kt + 2) % 3, kt + 2);   // 2-deep prefetch

        #pragma unroll 8
        for (int k = 0; k < 16; ++k) {
            // each read: 8 unique contiguous addrs x 16B = all 32 banks once, 8-lane broadcast
            float4 a0 = *(const float4*)&As[cur][k][wmb + r4];
            float4 a1 = *(const float4*)&As[cur][k][wmb + 32 + r4];
            float4 b0 = *(const float4*)&Bs[cur][k][wnb + c4];
            float4 b1 = *(const float4*)&Bs[cur][k][wnb + 32 + c4];
            float a[8] = {a0.x, a0.y, a0.z, a0.w, a1.x, a1.y, a1.z, a1.w};
            float b[8] = {b0.x, b0.y, b0.z, b0.w, b1.x, b1.y, b1.z, b1.w};
            #pragma unroll
            for (int i = 0; i < 8; ++i)
                #pragma unroll
                for (int j = 0; j < 8; ++j)
                    acc[i][j] += a[i] * b[j];
        }

        if (kt < KT16 - 1) {
            // need tile kt+1 resident past this barrier; keep tile kt+2's 4 loads in flight
            if (kt + 2 < KT16) asm volatile("s_waitcnt vmcnt(4)" ::: "memory");
            else               asm volatile("s_waitcnt vmcnt(0)" ::: "memory");
            __builtin_amdgcn_s_barrier();
            asm volatile("" ::: "memory");
        }
    }

    // epilogue (round-8 verbatim)
    #pragma unroll
    for (int h = 0; h < 2; ++h) {
        #pragma unroll
        for (int i = 0; i < 4; ++i) {
            const int m = m0 + wmb + h * 32 + r4 + i;
            if (m >= M_TOT) continue;
            float* cp = C + (size_t)m * COUT;
            const int col0 = n0 + wnb + c4;
            const int col1 = col0 + 32;
            const int ai = h * 4 + i;
            if (col0 < COUT)
                *(float4*)(cp + col0) = make_float4(acc[ai][0], acc[ai][1], acc[ai][2], acc[ai][3]);
            if (col1 < COUT)
                *(float4*)(cp + col1) = make_float4(acc[ai][4], acc[ai][5], acc[ai][6], acc[ai][7]);
        }
    }
}

// ---- fallback fp32 GEMM (round-3 proven, unchanged) ----
constexpr int BM = 128, BN = 128, BK = 32;
constexpr int LDA = BM + 4;

__global__ __launch_bounds__(256) void gemm_f32(
    const float* __restrict__ X, const float* __restrict__ W, float* __restrict__ C)
{
    __shared__ float As[BK][LDA];
    __shared__ float Bs[BK][LDA];

    const int mtile = blockIdx.x >> 2;
    const int ntile = blockIdx.x & 3;
    const int m0 = mtile * BM, n0 = ntile * BN;

    const int tid  = threadIdx.x;
    const int lane = tid & 63;
    const int wid  = tid >> 6;
    const int wmb  = (wid >> 1) << 6;
    const int wnb  = (wid & 1) << 6;
    const int r4   = (lane >> 3) << 2;
    const int c4   = (lane & 7) << 2;
    const int lr = tid >> 3;
    const int lk = (tid & 7) << 2;

    float acc[8][8];
    #pragma unroll
    for (int i = 0; i < 8; ++i)
        #pragma unroll
        for (int j = 0; j < 8; ++j) acc[i][j] = 0.f;

    for (int k0 = 0; k0 < CIN; k0 += BK) {
        const int kk = k0 + lk;
        const bool kv = (kk < CIN);
        #pragma unroll
        for (int p = 0; p < 4; ++p) {
            int row = p * 32 + lr;
            int m = m0 + row;
            float4 v = make_float4(0.f, 0.f, 0.f, 0.f);
            if (kv && m < M_TOT) v = *(const float4*)(X + (size_t)m * CIN + kk);
            As[lk + 0][row] = v.x; As[lk + 1][row] = v.y;
            As[lk + 2][row] = v.z; As[lk + 3][row] = v.w;
        }
        #pragma unroll
        for (int p = 0; p < 4; ++p) {
            int row = p * 32 + lr;
            int o = n0 + row;
            float4 v = make_float4(0.f, 0.f, 0.f, 0.f);
            if (kv && o < COUT) v = *(const float4*)(W + (size_t)o * CIN + kk);
            Bs[lk + 0][row] = v.x; Bs[lk + 1][row] = v.y;
            Bs[lk + 2][row] = v.z; Bs[lk + 3][row] = v.w;
        }
        __syncthreads();
        #pragma unroll 8
        for (int k = 0; k < BK; ++k) {
            float4 a0 = *(const float4*)&As[k][wmb + r4];
            float4 a1 = *(const float4*)&As[k][wmb + 32 + r4];
            float4 b0 = *(const float4*)&Bs[k][wnb + c4];
            float4 b1 = *(const float4*)&Bs[k][wnb + 32 + c4];
            float a[8] = {a0.x, a0.y, a0.z, a0.w, a1.x, a1.y, a1.z, a1.w};
            float b[8] = {b0.x, b0.y, b0.z, b0.w, b1.x, b1.y, b1.z, b1.w};
            #pragma unroll
            for (int i = 0; i < 8; ++i)
                #pragma unroll
                for (int j = 0; j < 8; ++j)
                    acc[i][j] += a[i] * b[j];
        }
        __syncthreads();
    }

    #pragma unroll
    for (int h = 0; h < 2; ++h) {
        #pragma unroll
        for (int i = 0; i < 4; ++i) {
            const int m = m0 + wmb + h * 32 + r4 + i;
            if (m >= M_TOT) continue;
            float* cp = C + (size_t)m * COUT;
            const int col0 = n0 + wnb + c4;
            const int col1 = col0 + 32;
            const int ai = h * 4 + i;
            if (col0 < COUT)
                *(float4*)(cp + col0) = make_float4(acc[ai][0], acc[ai][1], acc[ai][2], acc[ai][3]);
            if (col1 < COUT)
                *(float4*)(cp + col1) = make_float4(acc[ai][4], acc[ai][5], acc[ai][6], acc[ai][7]);
        }
    }
}

// ---- LIF scan, in place over C (identical to all passing rounds). threshold == 1 ----
__global__ __launch_bounds__(256) void lif_scan(
    const float* __restrict__ alpha, float* __restrict__ C)
{
    const int n = blockIdx.x * blockDim.x + threadIdx.x;
    if (n >= NB * COUT) return;
    const int b = n / COUT, o = n % COUT;
    const float a = alpha[n];
    float v = 0.f;
    float* p = C + (size_t)b * NT * COUT + o;

    constexpr int U = 10;
    for (int t0 = 0; t0 < NT; t0 += U) {
        float xl[U];
        #pragma unroll
        for (int u = 0; u < U; ++u) xl[u] = p[(size_t)(t0 + u) * COUT];
        float s[U];
        #pragma unroll
        for (int u = 0; u < U; ++u) {
            float vp = a * v + xl[u];
            vp = fmaxf(vp, -1.f);
            float sp = (vp >= 1.f) ? floorf(vp) : 0.f;
            v = vp - sp;
            s[u] = sp;
        }
        #pragma unroll
        for (int u = 0; u < U; ++u) p[(size_t)(t0 + u) * COUT] = s[u];
    }
}

extern "C" void kernel_launch(void* const* d_in, const int* in_sizes, int n_in,
                              void* d_out, int out_size, void* d_ws, size_t ws_size,
                              hipStream_t stream) {
    const float* X     = (const float*)d_in[0];   // [100,500,300]
    const float* W     = (const float*)d_in[1];   // [500,300]
    const float* alpha = (const float*)d_in[2];   // [50000]
    float* C = (float*)d_out;                     // [100,500,500]

    if (ws_size >= WS_NEED && d_ws != nullptr) {
        float* ws = (float*)d_ws;
        split_t<<<dim3(NPANEL), dim3(256), 0, stream>>>(X, W, ws);
        gemm_t<<<dim3(MTILES * NTILES), dim3(256), 0, stream>>>(ws, C);
    } else {
        gemm_f32<<<dim3(MTILES * 4), dim3(256), 0, stream>>>(X, W, C);
    }

    const int nneur = NB * COUT;
    lif_scan<<<dim3((nneur + 255) / 256), dim3(256), 0, stream>>>(alpha, C);
}

// Round 11
// 284.786 us; speedup vs baseline: 1.1260x; 1.0162x over previous
//
#include <hip/hip_runtime.h>
#include <hip/hip_bf16.h>
#include <stdint.h>

#define NB 100
#define NT 500
#define CIN 300
#define COUT 500
#define M_TOT (NB * NT)       // 50000
#define MTILES 391            // ceil(50000/128)
#define NTILES 4              // 512/128
#define KTILES 10             // panels of 32 k
#define KT16 19               // 19 x 16 = 304 >= 300 (k 300..303 zero no-ops)
#define NPANEL (MTILES * KTILES + NTILES * KTILES)   // 3950 panels of 4096 floats
#define WS_NEED ((size_t)NPANEL * 4096 * 4)          // 64,716,800 B

__device__ __forceinline__ void gload_lds16(const void* g, void* l) {
    __builtin_amdgcn_global_load_lds(
        (const __attribute__((address_space(1))) unsigned int*)g,
        (__attribute__((address_space(3))) unsigned int*)l,
        16, 0, 0);
}

// ---- pre-transpose X,W into panelized [panel][32 kk][128 m] f32 tiles (round-8 verbatim) ----
__global__ __launch_bounds__(256) void split_t(
    const float* __restrict__ X, const float* __restrict__ W, float* __restrict__ ws)
{
    const int bid = blockIdx.x;
    const int tid = threadIdx.x;
    const float* src; int rowbase, nrows, kt;
    if (bid < MTILES * KTILES) {
        src = X; rowbase = (bid / KTILES) * 128; nrows = M_TOT; kt = bid % KTILES;
    } else {
        const int w = bid - MTILES * KTILES;
        src = W; rowbase = (w / KTILES) * 128; nrows = COUT; kt = w % KTILES;
    }
    const int kk = tid >> 3;            // 0..31
    const int m0 = (tid & 7) * 16;      // 0..112
    const int k  = kt * 32 + kk;

    float v[16];
    #pragma unroll
    for (int j = 0; j < 16; ++j) {
        const int row = rowbase + m0 + j;
        v[j] = (row < nrows && k < CIN) ? src[(size_t)row * CIN + k] : 0.f;
    }
    float* out = ws + (size_t)bid * 4096 + (size_t)kk * 128 + m0;
    #pragma unroll
    for (int c = 0; c < 4; ++c)
        *(float4*)(out + c * 4) = make_float4(v[c*4], v[c*4+1], v[c*4+2], v[c*4+3]);
}

// ---- f32 GEMM: wave-autonomous pipeline. ZERO barriers; each wave stages its own
// private LDS double-buffer via global_load_lds and syncs only on its own vmcnt.
// Per-output fma chain identical to rounds 1/3/8/10 (ascending k, one fma per k).
__global__ __launch_bounds__(256) void gemm_t(
    const float* __restrict__ ws, float* __restrict__ C)
{
    // per wave: A[2][16][64] + B[2][16][64] = 16 KB; 4 waves -> 64 KB -> 2 blocks/CU
    __shared__ __align__(16) float Aw[4][2][16][64];
    __shared__ __align__(16) float Bw[4][2][16][64];

    const int mtile = blockIdx.x >> 2;      // ntile fastest: consecutive blocks share X panels
    const int ntile = blockIdx.x & 3;
    const int m0 = mtile * 128, n0 = ntile * 128;

    const int tid  = threadIdx.x;
    const int lane = tid & 63;
    const int wid  = tid >> 6;              // 4 waves: 2x2 grid of 64x64 wave tiles
    const int wmb  = (wid >> 1) << 6;       // 0 / 64  (A row base)
    const int wnb  = (wid & 1) << 6;        // 0 / 64  (B col base)
    const int r4   = (lane >> 3) << 2;      // 0,4,...,28
    const int c4   = (lane & 7) << 2;       // 0,4,...,28

    const float* Ap = ws + (size_t)(mtile * KTILES) * 4096;
    const float* Bp = ws + (size_t)(MTILES * KTILES + ntile * KTILES) * 4096;

    // staging lane geometry: per issue, 4 k-rows x 64 m; lane -> (kl, mq)
    const int kl = lane >> 4;               // 0..3
    const int mq = lane & 15;               // 0..15 (16B chunk within 64-float slice)
    const int aoff = kl * 128 + wmb + mq * 4;   // floats into a 32k-panel row block
    const int boff = kl * 128 + wnb + mq * 4;

    float acc[8][8];
    #pragma unroll
    for (int i = 0; i < 8; ++i)
        #pragma unroll
        for (int j = 0; j < 8; ++j) acc[i][j] = 0.f;

    // stage 16-k tile kt into private buffer buf: 8 gload_lds issues (4 A + 4 B)
    auto stage = [&](int buf, int kt) {
        const size_t tileoff = (size_t)(kt >> 1) * 4096 + (size_t)(kt & 1) * 2048;
        const float* xa = Ap + tileoff + aoff;
        const float* xb = Bp + tileoff + boff;
        char* la = (char*)&Aw[wid][buf][0][0] + lane * 16;
        char* lb = (char*)&Bw[wid][buf][0][0] + lane * 16;
        #pragma unroll
        for (int c = 0; c < 4; ++c) {
            gload_lds16(xa + c * 512, la + c * 1024);   // 4 k-rows (512 floats) per issue
            gload_lds16(xb + c * 512, lb + c * 1024);
        }
    };

    stage(0, 0);
    stage(1, 1);

    for (int kt = 0; kt < KT16; ++kt) {
        const int cur = kt & 1;
        // wait for tile kt resident; keep tile kt+1's 8 loads in flight (FIFO vmcnt)
        if (kt < KT16 - 1) asm volatile("s_waitcnt vmcnt(8)" ::: "memory");
        else               asm volatile("s_waitcnt vmcnt(0)" ::: "memory");

        #pragma unroll 8
        for (int k = 0; k < 16; ++k) {
            // each read: 8 unique contiguous addrs x 16B = all 32 banks once, 8-lane broadcast
            float4 a0 = *(const float4*)&Aw[wid][cur][k][r4];
            float4 a1 = *(const float4*)&Aw[wid][cur][k][32 + r4];
            float4 b0 = *(const float4*)&Bw[wid][cur][k][c4];
            float4 b1 = *(const float4*)&Bw[wid][cur][k][32 + c4];
            float a[8] = {a0.x, a0.y, a0.z, a0.w, a1.x, a1.y, a1.z, a1.w};
            float b[8] = {b0.x, b0.y, b0.z, b0.w, b1.x, b1.y, b1.z, b1.w};
            #pragma unroll
            for (int i = 0; i < 8; ++i)
                #pragma unroll
                for (int j = 0; j < 8; ++j)
                    acc[i][j] += a[i] * b[j];
        }

        if (kt + 2 < KT16) stage(cur, kt + 2);   // overwrite just-consumed private buffer
    }

    // epilogue (round-8 verbatim)
    #pragma unroll
    for (int h = 0; h < 2; ++h) {
        #pragma unroll
        for (int i = 0; i < 4; ++i) {
            const int m = m0 + wmb + h * 32 + r4 + i;
            if (m >= M_TOT) continue;
            float* cp = C + (size_t)m * COUT;
            const int col0 = n0 + wnb + c4;
            const int col1 = col0 + 32;
            const int ai = h * 4 + i;
            if (col0 < COUT)
                *(float4*)(cp + col0) = make_float4(acc[ai][0], acc[ai][1], acc[ai][2], acc[ai][3]);
            if (col1 < COUT)
                *(float4*)(cp + col1) = make_float4(acc[ai][4], acc[ai][5], acc[ai][6], acc[ai][7]);
        }
    }
}

// ---- fallback fp32 GEMM (round-3 proven, unchanged) ----
constexpr int BM = 128, BN = 128, BK = 32;
constexpr int LDA = BM + 4;

__global__ __launch_bounds__(256) void gemm_f32(
    const float* __restrict__ X, const float* __restrict__ W, float* __restrict__ C)
{
    __shared__ float As[BK][LDA];
    __shared__ float Bs[BK][LDA];

    const int mtile = blockIdx.x >> 2;
    const int ntile = blockIdx.x & 3;
    const int m0 = mtile * BM, n0 = ntile * BN;

    const int tid  = threadIdx.x;
    const int lane = tid & 63;
    const int wid  = tid >> 6;
    const int wmb  = (wid >> 1) << 6;
    const int wnb  = (wid & 1) << 6;
    const int r4   = (lane >> 3) << 2;
    const int c4   = (lane & 7) << 2;
    const int lr = tid >> 3;
    const int lk = (tid & 7) << 2;

    float acc[8][8];
    #pragma unroll
    for (int i = 0; i < 8; ++i)
        #pragma unroll
        for (int j = 0; j < 8; ++j) acc[i][j] = 0.f;

    for (int k0 = 0; k0 < CIN; k0 += BK) {
        const int kk = k0 + lk;
        const bool kv = (kk < CIN);
        #pragma unroll
        for (int p = 0; p < 4; ++p) {
            int row = p * 32 + lr;
            int m = m0 + row;
            float4 v = make_float4(0.f, 0.f, 0.f, 0.f);
            if (kv && m < M_TOT) v = *(const float4*)(X + (size_t)m * CIN + kk);
            As[lk + 0][row] = v.x; As[lk + 1][row] = v.y;
            As[lk + 2][row] = v.z; As[lk + 3][row] = v.w;
        }
        #pragma unroll
        for (int p = 0; p < 4; ++p) {
            int row = p * 32 + lr;
            int o = n0 + row;
            float4 v = make_float4(0.f, 0.f, 0.f, 0.f);
            if (kv && o < COUT) v = *(const float4*)(W + (size_t)o * CIN + kk);
            Bs[lk + 0][row] = v.x; Bs[lk + 1][row] = v.y;
            Bs[lk + 2][row] = v.z; Bs[lk + 3][row] = v.w;
        }
        __syncthreads();
        #pragma unroll 8
        for (int k = 0; k < BK; ++k) {
            float4 a0 = *(const float4*)&As[k][wmb + r4];
            float4 a1 = *(const float4*)&As[k][wmb + 32 + r4];
            float4 b0 = *(const float4*)&Bs[k][wnb + c4];
            float4 b1 = *(const float4*)&Bs[k][wnb + 32 + c4];
            float a[8] = {a0.x, a0.y, a0.z, a0.w, a1.x, a1.y, a1.z, a1.w};
            float b[8] = {b0.x, b0.y, b0.z, b0.w, b1.x, b1.y, b1.z, b1.w};
            #pragma unroll
            for (int i = 0; i < 8; ++i)
                #pragma unroll
                for (int j = 0; j < 8; ++j)
                    acc[i][j] += a[i] * b[j];
        }
        __syncthreads();
    }

    #pragma unroll
    for (int h = 0; h < 2; ++h) {
        #pragma unroll
        for (int i = 0; i < 4; ++i) {
            const int m = m0 + wmb + h * 32 + r4 + i;
            if (m >= M_TOT) continue;
            float* cp = C + (size_t)m * COUT;
            const int col0 = n0 + wnb + c4;
            const int col1 = col0 + 32;
            const int ai = h * 4 + i;
            if (col0 < COUT)
                *(float4*)(cp + col0) = make_float4(acc[ai][0], acc[ai][1], acc[ai][2], acc[ai][3]);
            if (col1 < COUT)
                *(float4*)(cp + col1) = make_float4(acc[ai][4], acc[ai][5], acc[ai][6], acc[ai][7]);
        }
    }
}

// ---- LIF scan, in place over C (identical to all passing rounds). threshold == 1 ----
__global__ __launch_bounds__(256) void lif_scan(
    const float* __restrict__ alpha, float* __restrict__ C)
{
    const int n = blockIdx.x * blockDim.x + threadIdx.x;
    if (n >= NB * COUT) return;
    const int b = n / COUT, o = n % COUT;
    const float a = alpha[n];
    float v = 0.f;
    float* p = C + (size_t)b * NT * COUT + o;

    constexpr int U = 10;
    for (int t0 = 0; t0 < NT; t0 += U) {
        float xl[U];
        #pragma unroll
        for (int u = 0; u < U; ++u) xl[u] = p[(size_t)(t0 + u) * COUT];
        float s[U];
        #pragma unroll
        for (int u = 0; u < U; ++u) {
            float vp = a * v + xl[u];
            vp = fmaxf(vp, -1.f);
            float sp = (vp >= 1.f) ? floorf(vp) : 0.f;
            v = vp - sp;
            s[u] = sp;
        }
        #pragma unroll
        for (int u = 0; u < U; ++u) p[(size_t)(t0 + u) * COUT] = s[u];
    }
}

extern "C" void kernel_launch(void* const* d_in, const int* in_sizes, int n_in,
                              void* d_out, int out_size, void* d_ws, size_t ws_size,
                              hipStream_t stream) {
    const float* X     = (const float*)d_in[0];   // [100,500,300]
    const float* W     = (const float*)d_in[1];   // [500,300]
    const float* alpha = (const float*)d_in[2];   // [50000]
    float* C = (float*)d_out;                     // [100,500,500]

    if (ws_size >= WS_NEED && d_ws != nullptr) {
        float* ws = (float*)d_ws;
        split_t<<<dim3(NPANEL), dim3(256), 0, stream>>>(X, W, ws);
        gemm_t<<<dim3(MTILES * NTILES), dim3(256), 0, stream>>>(ws, C);
    } else {
        gemm_f32<<<dim3(MTILES * 4), dim3(256), 0, stream>>>(X, W, C);
    }

    const int nneur = NB * COUT;
    lif_scan<<<dim3((nneur + 255) / 256), dim3(256), 0, stream>>>(alpha, C);
}